// Round 1
// baseline (1628.721 us; speedup 1.0000x reference)
//
#include <hip/hip_runtime.h>
#include <hip/hip_bf16.h>
#include <math.h>

// HGAT: 2-layer hypergraph attention. N nodes, M hyperedges, E incidence edges, D=128.
// Pipeline per layer: fc(x@W+b, fused n_attn=h@an) -> global softmax over n_attn[in_src]
// -> per-hyperedge segment sum (CSR by in_dst) -> e_attn=h_e@ae (fused) ->
// global softmax over ea[has_src]+na[has_dst] -> per-node segment sum (CSR by has_dst).
// CSR built once per call (index arrays shared by both layers).

typedef unsigned int u32;

#define NCONST 100000
#define MCONST 20000
#define ECONST 1600000

__device__ __forceinline__ u32 fkey(float f) {
  u32 u = __float_as_uint(f);
  return (u & 0x80000000u) ? ~u : (u | 0x80000000u);
}
__device__ __forceinline__ float fdec(u32 k) {
  return (k & 0x80000000u) ? __uint_as_float(k & 0x7FFFFFFFu) : __uint_as_float(~k);
}

// ---------------- CSR build ----------------
__global__ void k_hist(const int* __restrict__ dst, int n, int* __restrict__ cnt) {
  int i = blockIdx.x * blockDim.x + threadIdx.x;
  int st = gridDim.x * blockDim.x;
  for (; i < n; i += st) atomicAdd(&cnt[dst[i]], 1);
}

// block scans 1024 ints; writes inclusive into off[i+1]; block total into bsum
__global__ void k_scan1(const int* __restrict__ cnt, int n, int* __restrict__ off,
                        int* __restrict__ bsum) {
  __shared__ int sd[256];
  int t = threadIdx.x;
  int base = blockIdx.x * 1024 + t * 4;
  int v0 = (base + 0 < n) ? cnt[base + 0] : 0;
  int v1 = (base + 1 < n) ? cnt[base + 1] : 0;
  int v2 = (base + 2 < n) ? cnt[base + 2] : 0;
  int v3 = (base + 3 < n) ? cnt[base + 3] : 0;
  v1 += v0; v2 += v1; v3 += v2;
  int tot = v3;
  sd[t] = tot;
  __syncthreads();
  for (int o = 1; o < 256; o <<= 1) {
    int x = (t >= o) ? sd[t - o] : 0;
    __syncthreads();
    sd[t] += x;
    __syncthreads();
  }
  int excl = sd[t] - tot;
  if (base + 0 < n) off[base + 1] = v0 + excl;
  if (base + 1 < n) off[base + 2] = v1 + excl;
  if (base + 2 < n) off[base + 3] = v2 + excl;
  if (base + 3 < n) off[base + 4] = v3 + excl;
  if (t == 255) bsum[blockIdx.x] = sd[255];
}

__global__ void k_scan2(int* __restrict__ bsum, int nb) {
  __shared__ int sd[256];
  int t = threadIdx.x;
  int v = (t < nb) ? bsum[t] : 0;
  sd[t] = v;
  __syncthreads();
  for (int o = 1; o < 256; o <<= 1) {
    int x = (t >= o) ? sd[t - o] : 0;
    __syncthreads();
    sd[t] += x;
    __syncthreads();
  }
  if (t < nb) bsum[t] = sd[t] - v;  // exclusive
}

__global__ void k_scan3(int* __restrict__ off, int n, const int* __restrict__ bsum) {
  int i = blockIdx.x * blockDim.x + threadIdx.x;
  int st = gridDim.x * blockDim.x;
  if (blockIdx.x == 0 && threadIdx.x == 0) off[0] = 0;
  for (; i < n; i += st) off[i + 1] += bsum[i >> 10];
}

__global__ void k_scatter(const int* __restrict__ dst, int n, const int* __restrict__ off,
                          int* __restrict__ cur, int* __restrict__ eids) {
  int i = blockIdx.x * blockDim.x + threadIdx.x;
  int st = gridDim.x * blockDim.x;
  for (; i < n; i += st) {
    int d = dst[i];
    int p = atomicAdd(&cur[d], 1);
    eids[off[d] + p] = i;
  }
}

// ---------------- FC: h = x@W + b, na = h@an ----------------
__global__ __launch_bounds__(256, 1) void k_fc(
    const float* __restrict__ x, const float* __restrict__ W,
    const float* __restrict__ bias, const float* __restrict__ an,
    float* __restrict__ h, float* __restrict__ na, int nrows) {
  __shared__ float sW[128 * 128];    // [k][j]
  __shared__ float sxT[128][129];    // [k][r], padded
  __shared__ float sAn[128];
  __shared__ float sB[128];
  int tid = threadIdx.x;
  for (int i = tid * 4; i < 16384; i += 1024) {
    *(float4*)(sW + i) = *(const float4*)(W + i);
  }
  if (tid < 128) { sAn[tid] = an[tid]; sB[tid] = bias[tid]; }
  int r0 = blockIdx.x * 128;
  for (int i = tid; i < 128 * 32; i += 256) {
    int r = i >> 5, c = (i & 31) << 2;
    float4 v = make_float4(0.f, 0.f, 0.f, 0.f);
    if (r0 + r < nrows) v = *(const float4*)(x + (size_t)(r0 + r) * 128 + c);
    sxT[c + 0][r] = v.x; sxT[c + 1][r] = v.y; sxT[c + 2][r] = v.z; sxT[c + 3][r] = v.w;
  }
  __syncthreads();
  int tx = tid & 15, ty = tid >> 4;
  const int rb = ty * 8, cb = tx * 8;
  float acc[8][8];
#pragma unroll
  for (int i = 0; i < 8; ++i)
#pragma unroll
    for (int j = 0; j < 8; ++j) acc[i][j] = 0.f;
  for (int k = 0; k < 128; ++k) {
    float xv[8];
#pragma unroll
    for (int i = 0; i < 8; ++i) xv[i] = sxT[k][rb + i];
    float4 wa = *(const float4*)(sW + k * 128 + cb);
    float4 wb = *(const float4*)(sW + k * 128 + cb + 4);
    float wv[8] = {wa.x, wa.y, wa.z, wa.w, wb.x, wb.y, wb.z, wb.w};
#pragma unroll
    for (int i = 0; i < 8; ++i)
#pragma unroll
      for (int j = 0; j < 8; ++j) acc[i][j] = fmaf(xv[i], wv[j], acc[i][j]);
  }
  float anv[8], bv[8];
#pragma unroll
  for (int j = 0; j < 8; ++j) { anv[j] = sAn[cb + j]; bv[j] = sB[cb + j]; }
#pragma unroll
  for (int i = 0; i < 8; ++i) {
    int r = r0 + rb + i;
    float o0[8];
    float pa = 0.f;
#pragma unroll
    for (int j = 0; j < 8; ++j) { o0[j] = acc[i][j] + bv[j]; pa = fmaf(o0[j], anv[j], pa); }
    for (int o = 1; o < 16; o <<= 1) pa += __shfl_xor(pa, o, 64);
    if (r < nrows) {
      float4 A = make_float4(o0[0], o0[1], o0[2], o0[3]);
      float4 B = make_float4(o0[4], o0[5], o0[6], o0[7]);
      *(float4*)(h + (size_t)r * 128 + cb) = A;
      *(float4*)(h + (size_t)r * 128 + cb + 4) = B;
      if (tx == 0) na[r] = pa;
    }
  }
}

// ---------------- softmax reductions over E ----------------
__global__ void k_redmax1(const float* __restrict__ na, const int* __restrict__ src, int n,
                          u32* __restrict__ slot) {
  float m = -3.4e38f;
  int i = blockIdx.x * blockDim.x + threadIdx.x;
  int st = gridDim.x * blockDim.x;
  for (; i < n; i += st) m = fmaxf(m, na[src[i]]);
  for (int o = 1; o < 64; o <<= 1) m = fmaxf(m, __shfl_xor(m, o, 64));
  __shared__ float sm[4];
  if ((threadIdx.x & 63) == 0) sm[threadIdx.x >> 6] = m;
  __syncthreads();
  if (threadIdx.x == 0) {
    m = fmaxf(fmaxf(sm[0], sm[1]), fmaxf(sm[2], sm[3]));
    atomicMax(slot, fkey(m));
  }
}

__global__ void k_redsum1(const float* __restrict__ na, const int* __restrict__ src, int n,
                          const u32* __restrict__ slotmax, float* __restrict__ slotsum) {
  float mx = fdec(*slotmax);
  float s = 0.f;
  int i = blockIdx.x * blockDim.x + threadIdx.x;
  int st = gridDim.x * blockDim.x;
  for (; i < n; i += st) s += __expf(na[src[i]] - mx);
  for (int o = 1; o < 64; o <<= 1) s += __shfl_xor(s, o, 64);
  __shared__ float sm[4];
  if ((threadIdx.x & 63) == 0) sm[threadIdx.x >> 6] = s;
  __syncthreads();
  if (threadIdx.x == 0) atomicAdd(slotsum, sm[0] + sm[1] + sm[2] + sm[3]);
}

__global__ void k_redmax2(const float* __restrict__ ea, const float* __restrict__ na,
                          const int* __restrict__ hs, const int* __restrict__ hd, int n,
                          u32* __restrict__ slot) {
  float m = -3.4e38f;
  int i = blockIdx.x * blockDim.x + threadIdx.x;
  int st = gridDim.x * blockDim.x;
  for (; i < n; i += st) m = fmaxf(m, ea[hs[i]] + na[hd[i]]);
  for (int o = 1; o < 64; o <<= 1) m = fmaxf(m, __shfl_xor(m, o, 64));
  __shared__ float sm[4];
  if ((threadIdx.x & 63) == 0) sm[threadIdx.x >> 6] = m;
  __syncthreads();
  if (threadIdx.x == 0) {
    m = fmaxf(fmaxf(sm[0], sm[1]), fmaxf(sm[2], sm[3]));
    atomicMax(slot, fkey(m));
  }
}

__global__ void k_redsum2(const float* __restrict__ ea, const float* __restrict__ na,
                          const int* __restrict__ hs, const int* __restrict__ hd, int n,
                          const u32* __restrict__ slotmax, float* __restrict__ slotsum) {
  float mx = fdec(*slotmax);
  float s = 0.f;
  int i = blockIdx.x * blockDim.x + threadIdx.x;
  int st = gridDim.x * blockDim.x;
  for (; i < n; i += st) s += __expf(ea[hs[i]] + na[hd[i]] - mx);
  for (int o = 1; o < 64; o <<= 1) s += __shfl_xor(s, o, 64);
  __shared__ float sm[4];
  if ((threadIdx.x & 63) == 0) sm[threadIdx.x >> 6] = s;
  __syncthreads();
  if (threadIdx.x == 0) atomicAdd(slotsum, sm[0] + sm[1] + sm[2] + sm[3]);
}

__global__ void k_wnode(const float* __restrict__ na, const u32* __restrict__ slotmax,
                        const float* __restrict__ slotsum, float* __restrict__ w, int n) {
  float mx = fdec(*slotmax);
  float iz = 1.0f / (*slotsum);
  int i = blockIdx.x * blockDim.x + threadIdx.x;
  if (i < n) w[i] = __expf(na[i] - mx) * iz;
}

// ---------------- segment sums (one wave per segment) ----------------
__global__ __launch_bounds__(256) void k_segA(
    const float* __restrict__ h, const float* __restrict__ w,
    const int* __restrict__ in_src, const int* __restrict__ eids,
    const int* __restrict__ off, const float* __restrict__ ae,
    float* __restrict__ he, float* __restrict__ ea, int m_count) {
  int wid = (blockIdx.x << 2) + (threadIdx.x >> 6);
  int lane = threadIdx.x & 63;
  if (wid >= m_count) return;
  int s = off[wid], t = off[wid + 1];
  float ax = 0.f, ay = 0.f;
  for (int i = s; i < t; ++i) {
    int e = eids[i];
    int sr = in_src[e];
    float ww = w[sr];
    float2 v = *(const float2*)(h + (size_t)sr * 128 + lane * 2);
    ax = fmaf(ww, v.x, ax);
    ay = fmaf(ww, v.y, ay);
  }
  *(float2*)(he + (size_t)wid * 128 + lane * 2) = make_float2(ax, ay);
  float2 a = *(const float2*)(ae + lane * 2);
  float pa = ax * a.x + ay * a.y;
  for (int o = 1; o < 64; o <<= 1) pa += __shfl_xor(pa, o, 64);
  if (lane == 0) ea[wid] = pa;
}

__global__ __launch_bounds__(256) void k_segB(
    const float* __restrict__ he, const float* __restrict__ ea,
    const float* __restrict__ na, const int* __restrict__ hs,
    const int* __restrict__ eids, const int* __restrict__ off,
    const u32* __restrict__ slotmax, const float* __restrict__ slotsum,
    float* __restrict__ y, int n_count, int relu) {
  int wid = (blockIdx.x << 2) + (threadIdx.x >> 6);
  int lane = threadIdx.x & 63;
  if (wid >= n_count) return;
  float mx = fdec(*slotmax);
  float iz = 1.0f / (*slotsum);
  float nav = na[wid];
  int s = off[wid], t = off[wid + 1];
  float ax = 0.f, ay = 0.f;
  for (int i = s; i < t; ++i) {
    int e = eids[i];
    int sr = hs[e];
    float c = __expf(ea[sr] + nav - mx);
    float2 v = *(const float2*)(he + (size_t)sr * 128 + lane * 2);
    ax = fmaf(c, v.x, ax);
    ay = fmaf(c, v.y, ay);
  }
  ax *= iz;
  ay *= iz;
  if (relu) { ax = fmaxf(ax, 0.f); ay = fmaxf(ay, 0.f); }
  *(float2*)(y + (size_t)wid * 128 + lane * 2) = make_float2(ax, ay);
}

// ---------------- host ----------------
extern "C" void kernel_launch(void* const* d_in, const int* in_sizes, int n_in,
                              void* d_out, int out_size, void* d_ws, size_t ws_size,
                              hipStream_t stream) {
  const int N = NCONST, M = MCONST, E = ECONST;
  const float* x = (const float*)d_in[0];
  const int* in_src = (const int*)d_in[1];
  const int* in_dst = (const int*)d_in[2];
  const int* has_src = (const int*)d_in[3];
  const int* has_dst = (const int*)d_in[4];
  const float* W1 = (const float*)d_in[5];
  const float* b1 = (const float*)d_in[6];
  const float* an1 = (const float*)d_in[7];
  const float* ae1 = (const float*)d_in[8];
  const float* W2 = (const float*)d_in[9];
  const float* b2 = (const float*)d_in[10];
  const float* an2 = (const float*)d_in[11];
  const float* ae2 = (const float*)d_in[12];

  char* p = (char*)d_ws;
  auto alloc = [&](size_t bytes) {
    char* q = p;
    p += (bytes + 255) & ~(size_t)255;
    return q;
  };
  float* h = (float*)alloc((size_t)N * 128 * 4);
  float* he = (float*)alloc((size_t)M * 128 * 4);
  float* na = (float*)alloc((size_t)N * 4);
  float* ea = (float*)alloc((size_t)M * 4);
  float* wn = (float*)alloc((size_t)N * 4);
  int* off_in = (int*)alloc((size_t)(M + 1) * 4);
  int* off_has = (int*)alloc((size_t)(N + 1) * 4);
  int* eids_in = (int*)alloc((size_t)E * 4);
  int* eids_has = (int*)alloc((size_t)E * 4);
  int* bsum = (int*)alloc(256 * 4);
  char* zbase = p;
  int* cnt_in = (int*)alloc((size_t)M * 4);
  int* cur_in = (int*)alloc((size_t)M * 4);
  int* cnt_has = (int*)alloc((size_t)N * 4);
  int* cur_has = (int*)alloc((size_t)N * 4);
  u32* scal = (u32*)alloc(64);
  size_t zbytes = (size_t)(p - zbase);
  if ((size_t)(p - (char*)d_ws) > ws_size) return;  // insufficient workspace

  hipMemsetAsync(zbase, 0, zbytes, stream);

  // CSR build (index arrays shared by both layers)
  k_hist<<<1024, 256, 0, stream>>>(in_dst, E, cnt_in);
  k_hist<<<1024, 256, 0, stream>>>(has_dst, E, cnt_has);
  int nb_in = (M + 1023) / 1024;
  k_scan1<<<nb_in, 256, 0, stream>>>(cnt_in, M, off_in, bsum);
  k_scan2<<<1, 256, 0, stream>>>(bsum, nb_in);
  k_scan3<<<256, 256, 0, stream>>>(off_in, M, bsum);
  int nb_has = (N + 1023) / 1024;
  k_scan1<<<nb_has, 256, 0, stream>>>(cnt_has, N, off_has, bsum);
  k_scan2<<<1, 256, 0, stream>>>(bsum, nb_has);
  k_scan3<<<512, 256, 0, stream>>>(off_has, N, bsum);
  k_scatter<<<1024, 256, 0, stream>>>(in_dst, E, off_in, cur_in, eids_in);
  k_scatter<<<1024, 256, 0, stream>>>(has_dst, E, off_has, cur_has, eids_has);

  auto layer = [&](const float* xin, const float* W, const float* b, const float* an_,
                   const float* ae_, float* yout, int relu, int slot) {
    k_fc<<<(N + 127) / 128, 256, 0, stream>>>(xin, W, b, an_, h, na, N);
    k_redmax1<<<512, 256, 0, stream>>>(na, in_src, E, scal + slot);
    k_redsum1<<<512, 256, 0, stream>>>(na, in_src, E, scal + slot, (float*)(scal + slot + 1));
    k_wnode<<<(N + 255) / 256, 256, 0, stream>>>(na, scal + slot, (const float*)(scal + slot + 1),
                                                 wn, N);
    k_segA<<<(M + 3) / 4, 256, 0, stream>>>(h, wn, in_src, eids_in, off_in, ae_, he, ea, M);
    k_redmax2<<<512, 256, 0, stream>>>(ea, na, has_src, has_dst, E, scal + slot + 2);
    k_redsum2<<<512, 256, 0, stream>>>(ea, na, has_src, has_dst, E, scal + slot + 2,
                                       (float*)(scal + slot + 3));
    k_segB<<<(N + 3) / 4, 256, 0, stream>>>(he, ea, na, has_src, eids_has, off_has,
                                            scal + slot + 2, (const float*)(scal + slot + 3),
                                            yout, N, relu);
  };

  layer(x, W1, b1, an1, ae1, (float*)d_out, 1, 0);
  layer((const float*)d_out, W2, b2, an2, ae2, (float*)d_out, 0, 4);
}

// Round 3
// 932.074 us; speedup vs baseline: 1.7474x; 1.7474x over previous
//
#include <hip/hip_runtime.h>
#include <hip/hip_bf16.h>
#include <math.h>

// HGAT: 2-layer hypergraph attention. N nodes, M hyperedges, E incidence edges, D=128.
// R3: == R2 but h/he stored as BF16 (not fp16). The double global softmax shrinks values
// by ~1e-10 per layer; layer-2 h ~1e-9 underflows fp16 (min subnormal 6e-8) to zero.
// bf16 keeps fp32 exponent range at the same 2 B/elem gather traffic; accum stays fp32.

typedef unsigned int u32;
typedef unsigned short u16;
typedef u16 u16x8 __attribute__((ext_vector_type(8)));

#define NCONST 100000
#define MCONST 20000
#define ECONST 1600000

__device__ __forceinline__ u16 f2bf(float f) {  // RNE
  u32 u = __float_as_uint(f);
  u += 0x7FFFu + ((u >> 16) & 1u);
  return (u16)(u >> 16);
}
__device__ __forceinline__ float bf2f(u16 b) {
  return __uint_as_float(((u32)b) << 16);
}

// ---------------- CSR build ----------------
__global__ void k_hist(const int* __restrict__ dst, int n, int* __restrict__ cnt) {
  int i = blockIdx.x * blockDim.x + threadIdx.x;
  int st = gridDim.x * blockDim.x;
  for (; i < n; i += st) atomicAdd(&cnt[dst[i]], 1);
}

__global__ void k_scan1(const int* __restrict__ cnt, int n, int* __restrict__ off,
                        int* __restrict__ bsum) {
  __shared__ int sd[256];
  int t = threadIdx.x;
  int base = blockIdx.x * 1024 + t * 4;
  int v0 = (base + 0 < n) ? cnt[base + 0] : 0;
  int v1 = (base + 1 < n) ? cnt[base + 1] : 0;
  int v2 = (base + 2 < n) ? cnt[base + 2] : 0;
  int v3 = (base + 3 < n) ? cnt[base + 3] : 0;
  v1 += v0; v2 += v1; v3 += v2;
  int tot = v3;
  sd[t] = tot;
  __syncthreads();
  for (int o = 1; o < 256; o <<= 1) {
    int x = (t >= o) ? sd[t - o] : 0;
    __syncthreads();
    sd[t] += x;
    __syncthreads();
  }
  int excl = sd[t] - tot;
  if (base + 0 < n) off[base + 1] = v0 + excl;
  if (base + 1 < n) off[base + 2] = v1 + excl;
  if (base + 2 < n) off[base + 3] = v2 + excl;
  if (base + 3 < n) off[base + 4] = v3 + excl;
  if (t == 255) bsum[blockIdx.x] = sd[255];
}

__global__ void k_scan2(int* __restrict__ bsum, int nb) {
  __shared__ int sd[256];
  int t = threadIdx.x;
  int v = (t < nb) ? bsum[t] : 0;
  sd[t] = v;
  __syncthreads();
  for (int o = 1; o < 256; o <<= 1) {
    int x = (t >= o) ? sd[t - o] : 0;
    __syncthreads();
    sd[t] += x;
    __syncthreads();
  }
  if (t < nb) bsum[t] = sd[t] - v;  // exclusive
}

__global__ void k_scan3(int* __restrict__ off, int n, const int* __restrict__ bsum) {
  int i = blockIdx.x * blockDim.x + threadIdx.x;
  int st = gridDim.x * blockDim.x;
  if (blockIdx.x == 0 && threadIdx.x == 0) off[0] = 0;
  for (; i < n; i += st) off[i + 1] += bsum[i >> 10];
}

// scatter src values (not edge ids) into CSR order
__global__ void k_scatter(const int* __restrict__ dst, const int* __restrict__ srcv, int n,
                          const int* __restrict__ off, int* __restrict__ cur,
                          int* __restrict__ csrc) {
  int i = blockIdx.x * blockDim.x + threadIdx.x;
  int st = gridDim.x * blockDim.x;
  for (; i < n; i += st) {
    int d = dst[i];
    int p = atomicAdd(&cur[d], 1);
    csrc[off[d] + p] = srcv[i];
  }
}

// ---------------- FC: h = x@W + b (bf16 out), na = h@an ----------------
__global__ __launch_bounds__(256, 1) void k_fc(
    const float* __restrict__ x, const float* __restrict__ W,
    const float* __restrict__ bias, const float* __restrict__ an,
    u16* __restrict__ h, float* __restrict__ na, int nrows) {
  __shared__ float sW[128 * 128];    // [k][j]
  __shared__ float sxT[128][129];    // [k][r], padded
  __shared__ float sAn[128];
  __shared__ float sB[128];
  int tid = threadIdx.x;
  for (int i = tid * 4; i < 16384; i += 1024) {
    *(float4*)(sW + i) = *(const float4*)(W + i);
  }
  if (tid < 128) { sAn[tid] = an[tid]; sB[tid] = bias[tid]; }
  int r0 = blockIdx.x * 128;
  for (int i = tid; i < 128 * 32; i += 256) {
    int r = i >> 5, c = (i & 31) << 2;
    float4 v = make_float4(0.f, 0.f, 0.f, 0.f);
    if (r0 + r < nrows) v = *(const float4*)(x + (size_t)(r0 + r) * 128 + c);
    sxT[c + 0][r] = v.x; sxT[c + 1][r] = v.y; sxT[c + 2][r] = v.z; sxT[c + 3][r] = v.w;
  }
  __syncthreads();
  int tx = tid & 15, ty = tid >> 4;
  const int rb = ty * 8, cb = tx * 8;
  float acc[8][8];
#pragma unroll
  for (int i = 0; i < 8; ++i)
#pragma unroll
    for (int j = 0; j < 8; ++j) acc[i][j] = 0.f;
  for (int k = 0; k < 128; ++k) {
    float xv[8];
#pragma unroll
    for (int i = 0; i < 8; ++i) xv[i] = sxT[k][rb + i];
    float4 wa = *(const float4*)(sW + k * 128 + cb);
    float4 wb = *(const float4*)(sW + k * 128 + cb + 4);
    float wv[8] = {wa.x, wa.y, wa.z, wa.w, wb.x, wb.y, wb.z, wb.w};
#pragma unroll
    for (int i = 0; i < 8; ++i)
#pragma unroll
      for (int j = 0; j < 8; ++j) acc[i][j] = fmaf(xv[i], wv[j], acc[i][j]);
  }
  float anv[8], bv[8];
#pragma unroll
  for (int j = 0; j < 8; ++j) { anv[j] = sAn[cb + j]; bv[j] = sB[cb + j]; }
#pragma unroll
  for (int i = 0; i < 8; ++i) {
    int r = r0 + rb + i;
    float o0[8];
    float pa = 0.f;
#pragma unroll
    for (int j = 0; j < 8; ++j) { o0[j] = acc[i][j] + bv[j]; pa = fmaf(o0[j], anv[j], pa); }
    for (int o = 1; o < 16; o <<= 1) pa += __shfl_xor(pa, o, 64);
    if (r < nrows) {
      u16x8 o;
#pragma unroll
      for (int j = 0; j < 8; ++j) o[j] = f2bf(o0[j]);
      *(u16x8*)(h + (size_t)r * 128 + cb) = o;
      if (tx == 0) na[r] = pa;
    }
  }
}

// ---------------- online softmax reductions ----------------
__device__ __forceinline__ void merge_write(float m, float s, float2* __restrict__ pairs) {
  for (int o = 1; o < 64; o <<= 1) {
    float om = __shfl_xor(m, o, 64), os = __shfl_xor(s, o, 64);
    float nm = fmaxf(m, om);
    s = s * __expf(m - nm) + os * __expf(om - nm);
    m = nm;
  }
  __shared__ float sm[4], ss[4];
  int t = threadIdx.x;
  if ((t & 63) == 0) { sm[t >> 6] = m; ss[t >> 6] = s; }
  __syncthreads();
  if (t == 0) {
    for (int k = 1; k < 4; ++k) {
      float nm = fmaxf(m, sm[k]);
      s = s * __expf(m - nm) + ss[k] * __expf(sm[k] - nm);
      m = nm;
    }
    pairs[blockIdx.x] = make_float2(m, s);
  }
}

// softmax1 factorized over nodes: max over deg>0 nodes; sum = sum deg*exp(na-m)
__global__ void k_sm1(const float* __restrict__ na, const int* __restrict__ deg, int n,
                      float2* __restrict__ pairs) {
  float m = -1e30f, s = 0.f;
  int i = blockIdx.x * blockDim.x + threadIdx.x;
  int st = gridDim.x * blockDim.x;
  for (; i < n; i += st) {
    int d = deg[i];
    if (d > 0) {
      float xv = na[i];
      if (xv > m) { s *= __expf(m - xv); m = xv; }
      s += (float)d * __expf(xv - m);
    }
  }
  merge_write(m, s, pairs);
}

// softmax2 single online pass over E
__global__ void k_sm2(const float* __restrict__ ea, const float* __restrict__ na,
                      const int* __restrict__ hs, const int* __restrict__ hd, int n,
                      float2* __restrict__ pairs) {
  float m = -1e30f, s = 0.f;
  int i = blockIdx.x * blockDim.x + threadIdx.x;
  int st = gridDim.x * blockDim.x;
  for (; i < n; i += st) {
    float xv = ea[hs[i]] + na[hd[i]];
    if (xv > m) { s *= __expf(m - xv); m = xv; }
    s += __expf(xv - m);
  }
  merge_write(m, s, pairs);
}

__global__ void k_smfin(const float2* __restrict__ pairs, int nb, float* __restrict__ out) {
  int t = threadIdx.x;
  float m = -1e30f, s = 0.f;
  for (int i = t; i < nb; i += 256) {
    float2 pr = pairs[i];
    float nm = fmaxf(m, pr.x);
    s = s * __expf(m - nm) + pr.y * __expf(pr.x - nm);
    m = nm;
  }
  for (int o = 1; o < 64; o <<= 1) {
    float om = __shfl_xor(m, o, 64), os = __shfl_xor(s, o, 64);
    float nm = fmaxf(m, om);
    s = s * __expf(m - nm) + os * __expf(om - nm);
    m = nm;
  }
  __shared__ float sm[4], ss[4];
  if ((t & 63) == 0) { sm[t >> 6] = m; ss[t >> 6] = s; }
  __syncthreads();
  if (t == 0) {
    for (int k = 1; k < 4; ++k) {
      float nm = fmaxf(m, sm[k]);
      s = s * __expf(m - nm) + ss[k] * __expf(sm[k] - nm);
      m = nm;
    }
    out[0] = m;
    out[1] = s;
  }
}

__global__ void k_wnode(const float* __restrict__ na, const float* __restrict__ sc,
                        float* __restrict__ w, int n) {
  float mx = sc[0];
  float iz = 1.0f / sc[1];
  int i = blockIdx.x * blockDim.x + threadIdx.x;
  if (i < n) w[i] = __expf(na[i] - mx) * iz;
}

__global__ void k_pe(const float* __restrict__ ea, const float* __restrict__ sc,
                     float* __restrict__ pe, int m) {
  float mx = sc[0];
  float iz = 1.0f / sc[1];
  int i = blockIdx.x * blockDim.x + threadIdx.x;
  if (i < m) pe[i] = __expf(ea[i] - mx) * iz;
}

// ---------------- segment sums (one wave/segment, 16B/lane, 4 edges/iter) ----------------
__global__ __launch_bounds__(256) void k_segA(
    const u16* __restrict__ h, const float* __restrict__ w,
    const int* __restrict__ csrc, const int* __restrict__ off,
    const float* __restrict__ ae, u16* __restrict__ he,
    float* __restrict__ ea, int m_count) {
  int wid = (blockIdx.x << 2) + (threadIdx.x >> 6);
  if (wid >= m_count) return;
  int lane = threadIdx.x & 63;
  int sub = lane >> 4, cl = lane & 15;
  int s = off[wid], t = off[wid + 1];
  float ax[8];
#pragma unroll
  for (int j = 0; j < 8; ++j) ax[j] = 0.f;
  for (int i = s + sub; i < t; i += 4) {
    int sr = csrc[i];
    float ww = w[sr];
    u16x8 v = *(const u16x8*)(h + (size_t)sr * 128 + cl * 8);
#pragma unroll
    for (int j = 0; j < 8; ++j) ax[j] = fmaf(ww, bf2f(v[j]), ax[j]);
  }
#pragma unroll
  for (int j = 0; j < 8; ++j) {
    ax[j] += __shfl_xor(ax[j], 16, 64);
    ax[j] += __shfl_xor(ax[j], 32, 64);
  }
  float4 a0 = *(const float4*)(ae + cl * 8);
  float4 a1 = *(const float4*)(ae + cl * 8 + 4);
  float pa = ax[0] * a0.x + ax[1] * a0.y + ax[2] * a0.z + ax[3] * a0.w +
             ax[4] * a1.x + ax[5] * a1.y + ax[6] * a1.z + ax[7] * a1.w;
  pa += __shfl_xor(pa, 1, 64);
  pa += __shfl_xor(pa, 2, 64);
  pa += __shfl_xor(pa, 4, 64);
  pa += __shfl_xor(pa, 8, 64);
  if (sub == 0) {
    u16x8 o;
#pragma unroll
    for (int j = 0; j < 8; ++j) o[j] = f2bf(ax[j]);
    *(u16x8*)(he + (size_t)wid * 128 + cl * 8) = o;
    if (cl == 0) ea[wid] = pa;
  }
}

__global__ __launch_bounds__(256) void k_segB(
    const u16* __restrict__ he, const float* __restrict__ pe,
    const float* __restrict__ na, const int* __restrict__ csrc,
    const int* __restrict__ off, float* __restrict__ y, int n_count, int relu) {
  int wid = (blockIdx.x << 2) + (threadIdx.x >> 6);
  if (wid >= n_count) return;
  int lane = threadIdx.x & 63;
  int sub = lane >> 4, cl = lane & 15;
  float rf = __expf(na[wid]);  // exp(ea+na-mx)/Z = pe[sr]*exp(na)
  int s = off[wid], t = off[wid + 1];
  float ax[8];
#pragma unroll
  for (int j = 0; j < 8; ++j) ax[j] = 0.f;
  for (int i = s + sub; i < t; i += 4) {
    int sr = csrc[i];
    float c = pe[sr];
    u16x8 v = *(const u16x8*)(he + (size_t)sr * 128 + cl * 8);
#pragma unroll
    for (int j = 0; j < 8; ++j) ax[j] = fmaf(c, bf2f(v[j]), ax[j]);
  }
#pragma unroll
  for (int j = 0; j < 8; ++j) {
    ax[j] += __shfl_xor(ax[j], 16, 64);
    ax[j] += __shfl_xor(ax[j], 32, 64);
    ax[j] *= rf;
    if (relu) ax[j] = fmaxf(ax[j], 0.f);
  }
  if (sub == 0) {
    float4 A = make_float4(ax[0], ax[1], ax[2], ax[3]);
    float4 B = make_float4(ax[4], ax[5], ax[6], ax[7]);
    *(float4*)(y + (size_t)wid * 128 + cl * 8) = A;
    *(float4*)(y + (size_t)wid * 128 + cl * 8 + 4) = B;
  }
}

// ---------------- host ----------------
extern "C" void kernel_launch(void* const* d_in, const int* in_sizes, int n_in,
                              void* d_out, int out_size, void* d_ws, size_t ws_size,
                              hipStream_t stream) {
  const int N = NCONST, M = MCONST, E = ECONST;
  const float* x = (const float*)d_in[0];
  const int* in_src = (const int*)d_in[1];
  const int* in_dst = (const int*)d_in[2];
  const int* has_src = (const int*)d_in[3];
  const int* has_dst = (const int*)d_in[4];
  const float* W1 = (const float*)d_in[5];
  const float* b1 = (const float*)d_in[6];
  const float* an1 = (const float*)d_in[7];
  const float* ae1 = (const float*)d_in[8];
  const float* W2 = (const float*)d_in[9];
  const float* b2 = (const float*)d_in[10];
  const float* an2 = (const float*)d_in[11];
  const float* ae2 = (const float*)d_in[12];

  char* p = (char*)d_ws;
  auto alloc = [&](size_t bytes) {
    char* q = p;
    p += (bytes + 255) & ~(size_t)255;
    return q;
  };
  u16* h = (u16*)alloc((size_t)N * 128 * 2);
  u16* he = (u16*)alloc((size_t)M * 128 * 2);
  float* na = (float*)alloc((size_t)N * 4);
  float* ea = (float*)alloc((size_t)M * 4);
  float* wn = (float*)alloc((size_t)N * 4);
  float* pe = (float*)alloc((size_t)M * 4);
  int* off_in = (int*)alloc((size_t)(M + 1) * 4);
  int* off_has = (int*)alloc((size_t)(N + 1) * 4);
  int* csrc_in = (int*)alloc((size_t)E * 4);
  int* csrc_has = (int*)alloc((size_t)E * 4);
  int* bsum = (int*)alloc(256 * 4);
  float2* pairs = (float2*)alloc(256 * 8);
  float* scal = (float*)alloc(64);
  char* zbase = p;
  int* cnt_in = (int*)alloc((size_t)M * 4);
  int* cur_in = (int*)alloc((size_t)M * 4);
  int* cnt_has = (int*)alloc((size_t)N * 4);
  int* cur_has = (int*)alloc((size_t)N * 4);
  int* deg_src = (int*)alloc((size_t)N * 4);
  size_t zbytes = (size_t)(p - zbase);
  if ((size_t)(p - (char*)d_ws) > ws_size) return;  // insufficient workspace

  hipMemsetAsync(zbase, 0, zbytes, stream);

  // CSR build (index arrays shared by both layers)
  k_hist<<<1024, 256, 0, stream>>>(in_dst, E, cnt_in);
  k_hist<<<1024, 256, 0, stream>>>(has_dst, E, cnt_has);
  k_hist<<<1024, 256, 0, stream>>>(in_src, E, deg_src);
  int nb_in = (M + 1023) / 1024;
  k_scan1<<<nb_in, 256, 0, stream>>>(cnt_in, M, off_in, bsum);
  k_scan2<<<1, 256, 0, stream>>>(bsum, nb_in);
  k_scan3<<<256, 256, 0, stream>>>(off_in, M, bsum);
  int nb_has = (N + 1023) / 1024;
  k_scan1<<<nb_has, 256, 0, stream>>>(cnt_has, N, off_has, bsum);
  k_scan2<<<1, 256, 0, stream>>>(bsum, nb_has);
  k_scan3<<<512, 256, 0, stream>>>(off_has, N, bsum);
  k_scatter<<<1024, 256, 0, stream>>>(in_dst, in_src, E, off_in, cur_in, csrc_in);
  k_scatter<<<1024, 256, 0, stream>>>(has_dst, has_src, E, off_has, cur_has, csrc_has);

  auto layer = [&](const float* xin, const float* W, const float* b, const float* an_,
                   const float* ae_, float* yout, int relu) {
    k_fc<<<(N + 127) / 128, 256, 0, stream>>>(xin, W, b, an_, h, na, N);
    k_sm1<<<256, 256, 0, stream>>>(na, deg_src, N, pairs);
    k_smfin<<<1, 256, 0, stream>>>(pairs, 256, scal);
    k_wnode<<<(N + 255) / 256, 256, 0, stream>>>(na, scal, wn, N);
    k_segA<<<(M + 3) / 4, 256, 0, stream>>>(h, wn, csrc_in, off_in, ae_, he, ea, M);
    k_sm2<<<256, 256, 0, stream>>>(ea, na, has_src, has_dst, E, pairs);
    k_smfin<<<1, 256, 0, stream>>>(pairs, 256, scal + 2);
    k_pe<<<(M + 255) / 256, 256, 0, stream>>>(ea, scal + 2, pe, M);
    k_segB<<<(N + 3) / 4, 256, 0, stream>>>(he, pe, na, csrc_has, off_has, yout, N, relu);
  };

  layer(x, W1, b1, an1, ae1, (float*)d_out, 1);
  layer((const float*)d_out, W2, b2, an2, ae2, (float*)d_out, 0);
}